// Round 1
// baseline (1040.929 us; speedup 1.0000x reference)
//
#include <hip/hip_runtime.h>

constexpr int EMB  = 16;
constexpr int LAT  = 8;
constexpr int EDIM = 32;
constexpr int HID  = 64;

// ---------------------------------------------------------------------------
// Prep: transpose small weight matrices so per-k weight rows are contiguous
// (enables wide scalar loads in the hot kernels).
//   W1  (32x64) -> W1t  (64x32)
//   dW1 (16x64) -> dW1t (64x16)
// ---------------------------------------------------------------------------
__global__ void prep_kernel(const float* __restrict__ W1,
                            const float* __restrict__ dW1,
                            float* __restrict__ W1t,
                            float* __restrict__ dW1t) {
  int t = blockIdx.x * blockDim.x + threadIdx.x;
  if (t < EDIM * HID) { int i = t / HID, k = t % HID; W1t[k * EDIM + i] = W1[t]; }
  if (t < EMB * HID)  { int j = t / HID, k = t % HID; dW1t[k * EMB + j] = dW1[t]; }
}

// ---------------------------------------------------------------------------
// Kernel 1: fused edge MLP -> theta -> message -> scatter-add
// msg[o] = sum_i x_i*b2[i*8+o] + sum_k relu(h_k) * (sum_i x_i*W2[k][i*8+o])
// ---------------------------------------------------------------------------
__global__ __launch_bounds__(256) void edge_msg_kernel(
    const int* __restrict__ ei, const float* __restrict__ attr,
    const float* __restrict__ emb,
    const float* __restrict__ W1t, const float* __restrict__ b1,
    const float* __restrict__ W2,  const float* __restrict__ b2,
    float* __restrict__ agg, float* __restrict__ cnt, int E) {
  int e = blockIdx.x * blockDim.x + threadIdx.x;
  if (e >= E) return;
  int src = ei[e];
  int tgt = ei[E + e];

  // edge_attr row (32 floats), coalesced float4
  float x[EDIM];
  const float4* ap = reinterpret_cast<const float4*>(attr) + (size_t)e * (EDIM / 4);
#pragma unroll
  for (int i = 0; i < EDIM / 4; i++) {
    float4 v = ap[i];
    x[4 * i + 0] = v.x; x[4 * i + 1] = v.y; x[4 * i + 2] = v.z; x[4 * i + 3] = v.w;
  }

  // gathered source node embedding (16 floats)
  float xe[EMB];
  const float4* np4 = reinterpret_cast<const float4*>(emb) + (size_t)src * (EMB / 4);
#pragma unroll
  for (int i = 0; i < EMB / 4; i++) {
    float4 v = np4[i];
    xe[4 * i + 0] = v.x; xe[4 * i + 1] = v.y; xe[4 * i + 2] = v.z; xe[4 * i + 3] = v.w;
  }

  float msg[LAT];
#pragma unroll
  for (int o = 0; o < LAT; o++) msg[o] = 0.f;

  // bias-b2 contribution: msg[o] += xe[i] * b2[i*8+o]
#pragma unroll
  for (int i = 0; i < EMB; i++)
#pragma unroll
    for (int o = 0; o < LAT; o++) msg[o] = fmaf(xe[i], b2[i * LAT + o], msg[o]);

#pragma unroll 2
  for (int k = 0; k < HID; k++) {
    // h_k = relu(b1[k] + x . W1t[k])
    float a = b1[k];
    const float* w1r = W1t + k * EDIM;
#pragma unroll
    for (int i = 0; i < EDIM; i++) a = fmaf(x[i], w1r[i], a);
    a = fmaxf(a, 0.f);

    // u[o] = sum_i xe[i] * W2[k][i*8+o]
    const float* w2r = W2 + (size_t)k * (EMB * LAT);
    float u[LAT];
#pragma unroll
    for (int o = 0; o < LAT; o++) u[o] = 0.f;
#pragma unroll
    for (int i = 0; i < EMB; i++)
#pragma unroll
      for (int o = 0; o < LAT; o++) u[o] = fmaf(xe[i], w2r[i * LAT + o], u[o]);

#pragma unroll
    for (int o = 0; o < LAT; o++) msg[o] = fmaf(a, u[o], msg[o]);
  }

  // scatter-add (mean finished in latent_kernel)
  float* arow = agg + (size_t)tgt * LAT;
#pragma unroll
  for (int o = 0; o < LAT; o++) atomicAdd(arow + o, msg[o]);
  atomicAdd(cnt + tgt, 1.f);
}

// ---------------------------------------------------------------------------
// Kernel 2: latent[n] = node_emb[n] @ root_W + agg[n]/max(cnt,1) + conv_b
// ---------------------------------------------------------------------------
__global__ __launch_bounds__(256) void latent_kernel(
    const float* __restrict__ emb, const float* __restrict__ agg,
    const float* __restrict__ cnt, const float* __restrict__ rootW,
    const float* __restrict__ convb, float* __restrict__ latent, int N) {
  int n = blockIdx.x * blockDim.x + threadIdx.x;
  if (n >= N) return;

  float x[EMB];
  const float4* np4 = reinterpret_cast<const float4*>(emb) + (size_t)n * (EMB / 4);
#pragma unroll
  for (int i = 0; i < EMB / 4; i++) {
    float4 v = np4[i];
    x[4 * i + 0] = v.x; x[4 * i + 1] = v.y; x[4 * i + 2] = v.z; x[4 * i + 3] = v.w;
  }

  float inv = 1.f / fmaxf(cnt[n], 1.f);
  float r[LAT];
  const float* arow = agg + (size_t)n * LAT;
#pragma unroll
  for (int o = 0; o < LAT; o++) r[o] = fmaf(arow[o], inv, convb[o]);
#pragma unroll
  for (int i = 0; i < EMB; i++)
#pragma unroll
    for (int o = 0; o < LAT; o++) r[o] = fmaf(x[i], rootW[i * LAT + o], r[o]);

  float4* lp = reinterpret_cast<float4*>(latent) + (size_t)n * 2;
  lp[0] = make_float4(r[0], r[1], r[2], r[3]);
  lp[1] = make_float4(r[4], r[5], r[6], r[7]);
}

// ---------------------------------------------------------------------------
// Kernel 3: decoder  out = relu([latent[src],latent[tgt]] @ dW1 + db1) @ dW2 + db2
// ---------------------------------------------------------------------------
__global__ __launch_bounds__(256) void dec_kernel(
    const int* __restrict__ ei, const float* __restrict__ latent,
    const float* __restrict__ dW1t, const float* __restrict__ db1,
    const float* __restrict__ dW2,  const float* __restrict__ db2,
    float* __restrict__ out, int E) {
  int e = blockIdx.x * blockDim.x + threadIdx.x;
  if (e >= E) return;
  int src = ei[e];
  int tgt = ei[E + e];

  float in16[2 * LAT];
  {
    const float4* sp = reinterpret_cast<const float4*>(latent) + (size_t)src * 2;
    const float4* tp = reinterpret_cast<const float4*>(latent) + (size_t)tgt * 2;
    float4 a = sp[0], b = sp[1], c = tp[0], d = tp[1];
    in16[0] = a.x; in16[1] = a.y; in16[2] = a.z; in16[3] = a.w;
    in16[4] = b.x; in16[5] = b.y; in16[6] = b.z; in16[7] = b.w;
    in16[8] = c.x; in16[9] = c.y; in16[10] = c.z; in16[11] = c.w;
    in16[12] = d.x; in16[13] = d.y; in16[14] = d.z; in16[15] = d.w;
  }

  float acc[EDIM];
#pragma unroll
  for (int o = 0; o < EDIM; o++) acc[o] = db2[o];

#pragma unroll 2
  for (int k = 0; k < HID; k++) {
    float a = db1[k];
    const float* w = dW1t + k * (2 * LAT);
#pragma unroll
    for (int j = 0; j < 2 * LAT; j++) a = fmaf(in16[j], w[j], a);
    a = fmaxf(a, 0.f);
    const float* w2 = dW2 + k * EDIM;
#pragma unroll
    for (int o = 0; o < EDIM; o++) acc[o] = fmaf(a, w2[o], acc[o]);
  }

  float4* op = reinterpret_cast<float4*>(out) + (size_t)e * (EDIM / 4);
#pragma unroll
  for (int i = 0; i < EDIM / 4; i++)
    op[i] = make_float4(acc[4 * i + 0], acc[4 * i + 1], acc[4 * i + 2], acc[4 * i + 3]);
}

// ---------------------------------------------------------------------------
extern "C" void kernel_launch(void* const* d_in, const int* in_sizes, int n_in,
                              void* d_out, int out_size, void* d_ws, size_t ws_size,
                              hipStream_t stream) {
  const int*   ei    = (const int*)  d_in[0];
  const float* attr  = (const float*)d_in[1];
  const float* emb   = (const float*)d_in[2];
  const float* ewW1  = (const float*)d_in[3];
  const float* ewb1  = (const float*)d_in[4];
  const float* ewW2  = (const float*)d_in[5];
  const float* ewb2  = (const float*)d_in[6];
  const float* rootW = (const float*)d_in[7];
  const float* convb = (const float*)d_in[8];
  const float* dW1   = (const float*)d_in[9];
  const float* db1   = (const float*)d_in[10];
  const float* dW2   = (const float*)d_in[11];
  const float* db2   = (const float*)d_in[12];
  float* out = (float*)d_out;

  const int E = in_sizes[0] / 2;
  const int N = in_sizes[2] / EMB;

  float* agg  = (float*)d_ws;                 // N*8
  float* cnt  = agg + (size_t)N * LAT;        // N
  float* lat  = cnt + N;                      // N*8
  float* W1t  = lat + (size_t)N * LAT;        // 64*32
  float* dW1t = W1t + EDIM * HID;             // 64*16

  hipMemsetAsync(agg, 0, (size_t)(N * LAT + N) * sizeof(float), stream);
  prep_kernel<<<(EDIM * HID + 255) / 256, 256, 0, stream>>>(ewW1, dW1, W1t, dW1t);

  int blocks_e = (E + 255) / 256;
  edge_msg_kernel<<<blocks_e, 256, 0, stream>>>(ei, attr, emb, W1t, ewb1, ewW2, ewb2,
                                                agg, cnt, E);
  latent_kernel<<<(N + 255) / 256, 256, 0, stream>>>(emb, agg, cnt, rootW, convb, lat, N);
  dec_kernel<<<blocks_e, 256, 0, stream>>>(ei, lat, dW1t, db1, dW2, db2, out, E);
}

// Round 2
// 685.963 us; speedup vs baseline: 1.5175x; 1.5175x over previous
//
#include <hip/hip_runtime.h>

constexpr int EMB  = 16;
constexpr int LAT  = 8;
constexpr int EDIM = 32;
constexpr int HID  = 64;

constexpr int SCAN_BLK   = 256;
constexpr int SCAN_ITEMS = 4;
constexpr int SCAN_TILE  = SCAN_BLK * SCAN_ITEMS;  // 1024

// ---------------------------------------------------------------------------
// Prep: transpose small weight matrices so per-k weight rows are contiguous
// ---------------------------------------------------------------------------
__global__ void prep_kernel(const float* __restrict__ W1,
                            const float* __restrict__ dW1,
                            float* __restrict__ W1t,
                            float* __restrict__ dW1t) {
  int t = blockIdx.x * blockDim.x + threadIdx.x;
  if (t < EDIM * HID) { int i = t / HID, k = t % HID; W1t[k * EDIM + i] = W1[t]; }
  if (t < EMB * HID)  { int j = t / HID, k = t % HID; dW1t[k * EMB + j] = dW1[t]; }
}

// ---------------------------------------------------------------------------
// CSR build: in-degree histogram (int atomics, 1 per edge)
// ---------------------------------------------------------------------------
__global__ __launch_bounds__(256) void hist_kernel(const int* __restrict__ ei,
                                                   int* __restrict__ deg, int E) {
  int e = blockIdx.x * blockDim.x + threadIdx.x;
  if (e < E) atomicAdd(&deg[ei[E + e]], 1);
}

// Exclusive prefix sum over deg[N]: per-block local scan + block sums
__global__ __launch_bounds__(SCAN_BLK) void scan1_kernel(
    const int* __restrict__ deg, int* __restrict__ loc,
    int* __restrict__ bsum, int N) {
  __shared__ int sh[SCAN_BLK];
  int tid  = threadIdx.x;
  int base = blockIdx.x * SCAN_TILE + tid * SCAN_ITEMS;
  int v[SCAN_ITEMS];
  int s = 0;
#pragma unroll
  for (int j = 0; j < SCAN_ITEMS; j++) {
    v[j] = (base + j < N) ? deg[base + j] : 0;
    s += v[j];
  }
  sh[tid] = s;
  __syncthreads();
  for (int off = 1; off < SCAN_BLK; off <<= 1) {
    int t = (tid >= off) ? sh[tid - off] : 0;
    __syncthreads();
    sh[tid] += t;
    __syncthreads();
  }
  int p = sh[tid] - s;  // exclusive within block
#pragma unroll
  for (int j = 0; j < SCAN_ITEMS; j++) {
    if (base + j < N) loc[base + j] = p;
    p += v[j];
  }
  if (tid == SCAN_BLK - 1) bsum[blockIdx.x] = sh[tid];
}

__global__ void scan2_kernel(int* __restrict__ bsum, int NB) {
  if (threadIdx.x == 0 && blockIdx.x == 0) {
    int run = 0;
    for (int i = 0; i < NB; i++) { int t = bsum[i]; bsum[i] = run; run += t; }
  }
}

__global__ __launch_bounds__(256) void scan3_kernel(
    const int* __restrict__ loc, const int* __restrict__ bsum,
    int* __restrict__ offs, int* __restrict__ cursor, int N) {
  int i = blockIdx.x * blockDim.x + threadIdx.x;
  if (i < N) {
    int v = loc[i] + bsum[i / SCAN_TILE];
    offs[i] = v;
    cursor[i] = v;
  }
}

// ---------------------------------------------------------------------------
// Kernel 1: fused edge MLP -> theta -> message; store message into the
// target-grouped slot claimed by one returning int atomic (issued early so
// its latency hides under the k-loop).
// ---------------------------------------------------------------------------
__global__ __launch_bounds__(256) void edge_msg_kernel(
    const int* __restrict__ ei, const float* __restrict__ attr,
    const float* __restrict__ emb,
    const float* __restrict__ W1t, const float* __restrict__ b1,
    const float* __restrict__ W2,  const float* __restrict__ b2,
    int* __restrict__ cursor, float* __restrict__ ms, int E) {
  int e = blockIdx.x * blockDim.x + threadIdx.x;
  if (e >= E) return;
  int src = ei[e];
  int tgt = ei[E + e];
  int pos = atomicAdd(&cursor[tgt], 1);  // early: latency hidden by compute

  float x[EDIM];
  const float4* ap = reinterpret_cast<const float4*>(attr) + (size_t)e * (EDIM / 4);
#pragma unroll
  for (int i = 0; i < EDIM / 4; i++) {
    float4 v = ap[i];
    x[4 * i + 0] = v.x; x[4 * i + 1] = v.y; x[4 * i + 2] = v.z; x[4 * i + 3] = v.w;
  }

  float xe[EMB];
  const float4* np4 = reinterpret_cast<const float4*>(emb) + (size_t)src * (EMB / 4);
#pragma unroll
  for (int i = 0; i < EMB / 4; i++) {
    float4 v = np4[i];
    xe[4 * i + 0] = v.x; xe[4 * i + 1] = v.y; xe[4 * i + 2] = v.z; xe[4 * i + 3] = v.w;
  }

  float msg[LAT];
#pragma unroll
  for (int o = 0; o < LAT; o++) msg[o] = 0.f;

  // b2 contribution: msg[o] += xe[i] * b2[i*8+o]
#pragma unroll
  for (int i = 0; i < EMB; i++)
#pragma unroll
    for (int o = 0; o < LAT; o++) msg[o] = fmaf(xe[i], b2[i * LAT + o], msg[o]);

#pragma unroll 2
  for (int k = 0; k < HID; k++) {
    float a = b1[k];
    const float* w1r = W1t + k * EDIM;
#pragma unroll
    for (int i = 0; i < EDIM; i++) a = fmaf(x[i], w1r[i], a);
    a = fmaxf(a, 0.f);

    const float* w2r = W2 + (size_t)k * (EMB * LAT);
    float u[LAT];
#pragma unroll
    for (int o = 0; o < LAT; o++) u[o] = 0.f;
#pragma unroll
    for (int i = 0; i < EMB; i++)
#pragma unroll
      for (int o = 0; o < LAT; o++) u[o] = fmaf(xe[i], w2r[i * LAT + o], u[o]);

#pragma unroll
    for (int o = 0; o < LAT; o++) msg[o] = fmaf(a, u[o], msg[o]);
  }

  float4* mp = reinterpret_cast<float4*>(ms) + (size_t)pos * 2;
  mp[0] = make_float4(msg[0], msg[1], msg[2], msg[3]);
  mp[1] = make_float4(msg[4], msg[5], msg[6], msg[7]);
}

// ---------------------------------------------------------------------------
// Kernel 2: per node, sum its contiguous message rows, finish mean + root
// ---------------------------------------------------------------------------
__global__ __launch_bounds__(256) void agg_latent_kernel(
    const float* __restrict__ emb, const float* __restrict__ ms,
    const int* __restrict__ offs, const int* __restrict__ deg,
    const float* __restrict__ rootW, const float* __restrict__ convb,
    float* __restrict__ latent, int N) {
  int n = blockIdx.x * blockDim.x + threadIdx.x;
  if (n >= N) return;
  int start = offs[n];
  int d = deg[n];

  float r[LAT];
#pragma unroll
  for (int o = 0; o < LAT; o++) r[o] = 0.f;

  const float4* mp = reinterpret_cast<const float4*>(ms);
  for (int j = 0; j < d; j++) {
    float4 a = mp[(size_t)(start + j) * 2];
    float4 b = mp[(size_t)(start + j) * 2 + 1];
    r[0] += a.x; r[1] += a.y; r[2] += a.z; r[3] += a.w;
    r[4] += b.x; r[5] += b.y; r[6] += b.z; r[7] += b.w;
  }

  float inv = 1.f / fmaxf((float)d, 1.f);
#pragma unroll
  for (int o = 0; o < LAT; o++) r[o] = fmaf(r[o], inv, convb[o]);

  float x[EMB];
  const float4* np4 = reinterpret_cast<const float4*>(emb) + (size_t)n * (EMB / 4);
#pragma unroll
  for (int i = 0; i < EMB / 4; i++) {
    float4 v = np4[i];
    x[4 * i + 0] = v.x; x[4 * i + 1] = v.y; x[4 * i + 2] = v.z; x[4 * i + 3] = v.w;
  }
#pragma unroll
  for (int i = 0; i < EMB; i++)
#pragma unroll
    for (int o = 0; o < LAT; o++) r[o] = fmaf(x[i], rootW[i * LAT + o], r[o]);

  float4* lp = reinterpret_cast<float4*>(latent) + (size_t)n * 2;
  lp[0] = make_float4(r[0], r[1], r[2], r[3]);
  lp[1] = make_float4(r[4], r[5], r[6], r[7]);
}

// ---------------------------------------------------------------------------
// Kernel 3: decoder
// ---------------------------------------------------------------------------
__global__ __launch_bounds__(256) void dec_kernel(
    const int* __restrict__ ei, const float* __restrict__ latent,
    const float* __restrict__ dW1t, const float* __restrict__ db1,
    const float* __restrict__ dW2,  const float* __restrict__ db2,
    float* __restrict__ out, int E) {
  int e = blockIdx.x * blockDim.x + threadIdx.x;
  if (e >= E) return;
  int src = ei[e];
  int tgt = ei[E + e];

  float in16[2 * LAT];
  {
    const float4* sp = reinterpret_cast<const float4*>(latent) + (size_t)src * 2;
    const float4* tp = reinterpret_cast<const float4*>(latent) + (size_t)tgt * 2;
    float4 a = sp[0], b = sp[1], c = tp[0], d = tp[1];
    in16[0] = a.x; in16[1] = a.y; in16[2] = a.z; in16[3] = a.w;
    in16[4] = b.x; in16[5] = b.y; in16[6] = b.z; in16[7] = b.w;
    in16[8] = c.x; in16[9] = c.y; in16[10] = c.z; in16[11] = c.w;
    in16[12] = d.x; in16[13] = d.y; in16[14] = d.z; in16[15] = d.w;
  }

  float acc[EDIM];
#pragma unroll
  for (int o = 0; o < EDIM; o++) acc[o] = db2[o];

#pragma unroll 2
  for (int k = 0; k < HID; k++) {
    float a = db1[k];
    const float* w = dW1t + k * (2 * LAT);
#pragma unroll
    for (int j = 0; j < 2 * LAT; j++) a = fmaf(in16[j], w[j], a);
    a = fmaxf(a, 0.f);
    const float* w2 = dW2 + k * EDIM;
#pragma unroll
    for (int o = 0; o < EDIM; o++) acc[o] = fmaf(a, w2[o], acc[o]);
  }

  float4* op = reinterpret_cast<float4*>(out) + (size_t)e * (EDIM / 4);
#pragma unroll
  for (int i = 0; i < EDIM / 4; i++)
    op[i] = make_float4(acc[4 * i + 0], acc[4 * i + 1], acc[4 * i + 2], acc[4 * i + 3]);
}

// ---------------------------------------------------------------------------
// Fallback (round-1 atomic path) in case ws_size is too small for CSR buffers
// ---------------------------------------------------------------------------
__global__ __launch_bounds__(256) void edge_msg_atomic_kernel(
    const int* __restrict__ ei, const float* __restrict__ attr,
    const float* __restrict__ emb,
    const float* __restrict__ W1t, const float* __restrict__ b1,
    const float* __restrict__ W2,  const float* __restrict__ b2,
    float* __restrict__ agg, float* __restrict__ cnt, int E) {
  int e = blockIdx.x * blockDim.x + threadIdx.x;
  if (e >= E) return;
  int src = ei[e];
  int tgt = ei[E + e];

  float x[EDIM];
  const float4* ap = reinterpret_cast<const float4*>(attr) + (size_t)e * (EDIM / 4);
#pragma unroll
  for (int i = 0; i < EDIM / 4; i++) {
    float4 v = ap[i];
    x[4 * i + 0] = v.x; x[4 * i + 1] = v.y; x[4 * i + 2] = v.z; x[4 * i + 3] = v.w;
  }
  float xe[EMB];
  const float4* np4 = reinterpret_cast<const float4*>(emb) + (size_t)src * (EMB / 4);
#pragma unroll
  for (int i = 0; i < EMB / 4; i++) {
    float4 v = np4[i];
    xe[4 * i + 0] = v.x; xe[4 * i + 1] = v.y; xe[4 * i + 2] = v.z; xe[4 * i + 3] = v.w;
  }
  float msg[LAT];
#pragma unroll
  for (int o = 0; o < LAT; o++) msg[o] = 0.f;
#pragma unroll
  for (int i = 0; i < EMB; i++)
#pragma unroll
    for (int o = 0; o < LAT; o++) msg[o] = fmaf(xe[i], b2[i * LAT + o], msg[o]);
#pragma unroll 2
  for (int k = 0; k < HID; k++) {
    float a = b1[k];
    const float* w1r = W1t + k * EDIM;
#pragma unroll
    for (int i = 0; i < EDIM; i++) a = fmaf(x[i], w1r[i], a);
    a = fmaxf(a, 0.f);
    const float* w2r = W2 + (size_t)k * (EMB * LAT);
    float u[LAT];
#pragma unroll
    for (int o = 0; o < LAT; o++) u[o] = 0.f;
#pragma unroll
    for (int i = 0; i < EMB; i++)
#pragma unroll
      for (int o = 0; o < LAT; o++) u[o] = fmaf(xe[i], w2r[i * LAT + o], u[o]);
#pragma unroll
    for (int o = 0; o < LAT; o++) msg[o] = fmaf(a, u[o], msg[o]);
  }
  float* arow = agg + (size_t)tgt * LAT;
#pragma unroll
  for (int o = 0; o < LAT; o++) atomicAdd(arow + o, msg[o]);
  atomicAdd(cnt + tgt, 1.f);
}

__global__ __launch_bounds__(256) void latent_fb_kernel(
    const float* __restrict__ emb, const float* __restrict__ agg,
    const float* __restrict__ cnt, const float* __restrict__ rootW,
    const float* __restrict__ convb, float* __restrict__ latent, int N) {
  int n = blockIdx.x * blockDim.x + threadIdx.x;
  if (n >= N) return;
  float x[EMB];
  const float4* np4 = reinterpret_cast<const float4*>(emb) + (size_t)n * (EMB / 4);
#pragma unroll
  for (int i = 0; i < EMB / 4; i++) {
    float4 v = np4[i];
    x[4 * i + 0] = v.x; x[4 * i + 1] = v.y; x[4 * i + 2] = v.z; x[4 * i + 3] = v.w;
  }
  float inv = 1.f / fmaxf(cnt[n], 1.f);
  float r[LAT];
  const float* arow = agg + (size_t)n * LAT;
#pragma unroll
  for (int o = 0; o < LAT; o++) r[o] = fmaf(arow[o], inv, convb[o]);
#pragma unroll
  for (int i = 0; i < EMB; i++)
#pragma unroll
    for (int o = 0; o < LAT; o++) r[o] = fmaf(x[i], rootW[i * LAT + o], r[o]);
  float4* lp = reinterpret_cast<float4*>(latent) + (size_t)n * 2;
  lp[0] = make_float4(r[0], r[1], r[2], r[3]);
  lp[1] = make_float4(r[4], r[5], r[6], r[7]);
}

// ---------------------------------------------------------------------------
extern "C" void kernel_launch(void* const* d_in, const int* in_sizes, int n_in,
                              void* d_out, int out_size, void* d_ws, size_t ws_size,
                              hipStream_t stream) {
  const int*   ei    = (const int*)  d_in[0];
  const float* attr  = (const float*)d_in[1];
  const float* emb   = (const float*)d_in[2];
  const float* ewW1  = (const float*)d_in[3];
  const float* ewb1  = (const float*)d_in[4];
  const float* ewW2  = (const float*)d_in[5];
  const float* ewb2  = (const float*)d_in[6];
  const float* rootW = (const float*)d_in[7];
  const float* convb = (const float*)d_in[8];
  const float* dW1   = (const float*)d_in[9];
  const float* db1   = (const float*)d_in[10];
  const float* dW2   = (const float*)d_in[11];
  const float* db2   = (const float*)d_in[12];
  float* out = (float*)d_out;

  const int E  = in_sizes[0] / 2;
  const int N  = in_sizes[2] / EMB;
  const int NB = (N + SCAN_TILE - 1) / SCAN_TILE;

  const int blocks_e = (E + 255) / 256;
  const int blocks_n = (N + 255) / 256;

  // CSR-path workspace layout
  size_t need = (size_t)E * LAT * 4        // msg_sorted
              + (size_t)N * LAT * 4        // latent
              + (size_t)N * 4 * 4          // deg, loc, offs, cursor
              + (size_t)NB * 4
              + (EDIM * HID + EMB * HID) * 4 + 1024;

  if (ws_size >= need) {
    float* ms     = (float*)d_ws;                    // E*8
    float* lat    = ms + (size_t)E * LAT;            // N*8
    int*   deg    = (int*)(lat + (size_t)N * LAT);   // N
    int*   loc    = deg + N;                         // N
    int*   offs   = loc + N;                         // N
    int*   cursor = offs + N;                        // N
    int*   bsum   = cursor + N;                      // NB
    float* W1t    = (float*)(bsum + NB);             // 64*32
    float* dW1t   = W1t + EDIM * HID;                // 64*16

    hipMemsetAsync(deg, 0, (size_t)N * sizeof(int), stream);
    prep_kernel<<<(EDIM * HID + 255) / 256, 256, 0, stream>>>(ewW1, dW1, W1t, dW1t);
    hist_kernel<<<blocks_e, 256, 0, stream>>>(ei, deg, E);
    scan1_kernel<<<NB, SCAN_BLK, 0, stream>>>(deg, loc, bsum, N);
    scan2_kernel<<<1, 64, 0, stream>>>(bsum, NB);
    scan3_kernel<<<blocks_n, 256, 0, stream>>>(loc, bsum, offs, cursor, N);
    edge_msg_kernel<<<blocks_e, 256, 0, stream>>>(ei, attr, emb, W1t, ewb1, ewW2, ewb2,
                                                  cursor, ms, E);
    agg_latent_kernel<<<blocks_n, 256, 0, stream>>>(emb, ms, offs, deg, rootW, convb,
                                                    lat, N);
    dec_kernel<<<blocks_e, 256, 0, stream>>>(ei, lat, dW1t, db1, dW2, db2, out, E);
  } else {
    // fallback: round-1 atomic path (needs ~7.5 MB)
    float* agg  = (float*)d_ws;
    float* cnt  = agg + (size_t)N * LAT;
    float* lat  = cnt + N;
    float* W1t  = lat + (size_t)N * LAT;
    float* dW1t = W1t + EDIM * HID;

    hipMemsetAsync(agg, 0, (size_t)(N * LAT + N) * sizeof(float), stream);
    prep_kernel<<<(EDIM * HID + 255) / 256, 256, 0, stream>>>(ewW1, dW1, W1t, dW1t);
    edge_msg_atomic_kernel<<<blocks_e, 256, 0, stream>>>(ei, attr, emb, W1t, ewb1,
                                                         ewW2, ewb2, agg, cnt, E);
    latent_fb_kernel<<<blocks_n, 256, 0, stream>>>(emb, agg, cnt, rootW, convb, lat, N);
    dec_kernel<<<blocks_e, 256, 0, stream>>>(ei, lat, dW1t, db1, dW2, db2, out, E);
  }
}

// Round 3
// 363.691 us; speedup vs baseline: 2.8621x; 1.8861x over previous
//
#include <hip/hip_runtime.h>
#include <hip/hip_bf16.h>

typedef __attribute__((ext_vector_type(8))) short  s16x8;
typedef __attribute__((ext_vector_type(4))) float  f32x4;

constexpr int EMB  = 16;
constexpr int LAT  = 8;
constexpr int EDIM = 32;
constexpr int HID  = 64;

constexpr int SCAN_BLK   = 256;
constexpr int SCAN_ITEMS = 4;
constexpr int SCAN_TILE  = SCAN_BLK * SCAN_ITEMS;  // 1024

__device__ __forceinline__ short f2b(float f) {
  __hip_bfloat16 h = __float2bfloat16(f);
  return __builtin_bit_cast(short, h);
}

// ---------------------------------------------------------------------------
// Prep: bf16 col-major transposes of all weight matrices.
//  W1c  [64 col][32 k] <- ew_W1 (32,64)
//  W2c  [128 col][64 k] <- ew_W2 (64,128)
//  dW1c [64 col][16 k] <- dec_W1 (16,64)
//  dW2c [32 col][64 k] <- dec_W2 (64,32)
// ---------------------------------------------------------------------------
__global__ void prep_kernel(const float* __restrict__ W1, const float* __restrict__ W2,
                            const float* __restrict__ dW1, const float* __restrict__ dW2,
                            short* __restrict__ W1c, short* __restrict__ W2c,
                            short* __restrict__ dW1c, short* __restrict__ dW2c) {
  int t = blockIdx.x * blockDim.x + threadIdx.x;
  if (t < 64 * 32)  { int c = t / 32, k = t % 32; W1c[t]  = f2b(W1[k * 64 + c]); }
  if (t < 128 * 64) { int c = t / 64, k = t % 64; W2c[t]  = f2b(W2[k * 128 + c]); }
  if (t < 64 * 16)  { int c = t / 16, k = t % 16; dW1c[t] = f2b(dW1[k * 64 + c]); }
  if (t < 32 * 64)  { int c = t / 64, k = t % 64; dW2c[t] = f2b(dW2[k * 32 + c]); }
}

// ---------------------------------------------------------------------------
// CSR build: histogram + exclusive scan (unchanged from round 2)
// ---------------------------------------------------------------------------
__global__ __launch_bounds__(256) void hist_kernel(const int* __restrict__ ei,
                                                   int* __restrict__ deg, int E) {
  int e = blockIdx.x * blockDim.x + threadIdx.x;
  if (e < E) atomicAdd(&deg[ei[E + e]], 1);
}

__global__ __launch_bounds__(SCAN_BLK) void scan1_kernel(
    const int* __restrict__ deg, int* __restrict__ loc,
    int* __restrict__ bsum, int N) {
  __shared__ int sh[SCAN_BLK];
  int tid  = threadIdx.x;
  int base = blockIdx.x * SCAN_TILE + tid * SCAN_ITEMS;
  int v[SCAN_ITEMS];
  int s = 0;
#pragma unroll
  for (int j = 0; j < SCAN_ITEMS; j++) {
    v[j] = (base + j < N) ? deg[base + j] : 0;
    s += v[j];
  }
  sh[tid] = s;
  __syncthreads();
  for (int off = 1; off < SCAN_BLK; off <<= 1) {
    int t = (tid >= off) ? sh[tid - off] : 0;
    __syncthreads();
    sh[tid] += t;
    __syncthreads();
  }
  int p = sh[tid] - s;
#pragma unroll
  for (int j = 0; j < SCAN_ITEMS; j++) {
    if (base + j < N) loc[base + j] = p;
    p += v[j];
  }
  if (tid == SCAN_BLK - 1) bsum[blockIdx.x] = sh[tid];
}

__global__ void scan2_kernel(int* __restrict__ bsum, int NB) {
  if (threadIdx.x == 0 && blockIdx.x == 0) {
    int run = 0;
    for (int i = 0; i < NB; i++) { int t = bsum[i]; bsum[i] = run; run += t; }
  }
}

__global__ __launch_bounds__(256) void scan3_kernel(
    const int* __restrict__ loc, const int* __restrict__ bsum,
    int* __restrict__ offs, int* __restrict__ cursor, int N) {
  int i = blockIdx.x * blockDim.x + threadIdx.x;
  if (i < N) {
    int v = loc[i] + bsum[i / SCAN_TILE];
    offs[i] = v;
    cursor[i] = v;
  }
}

// ---------------------------------------------------------------------------
// Encoder: MFMA. Block = 256 edges, 4 independent waves x 64 edges (4 M-tiles).
// GEMM1: (16,32)@(32,64) relu -> H (LDS, XOR-swizzled) -> GEMM2: (16,64)@(64,128)
// epilogue: msg[o] = sum_i xe[i]*(G[i*8+o]+b2[i*8+o]), pair-reduce via shfl_xor(8).
// k-mapping g(l,j)=(l>>4)*8+j used consistently for A and B (permutation-safe).
// ---------------------------------------------------------------------------
__global__ __launch_bounds__(256, 2) void enc_mfma_kernel(
    const int* __restrict__ ei, const float* __restrict__ attr,
    const float* __restrict__ emb,
    const short* __restrict__ W1c, const float* __restrict__ b1,
    const short* __restrict__ W2c, const float* __restrict__ b2,
    int* __restrict__ cursor, float* __restrict__ ms, int E) {
  __shared__ float xe_lds[4][64][17];   // +1 pad: conflict-free scalar reads
  __shared__ int   pos_lds[4][64];
  __shared__ short H_lds[4][16 * 64];   // per-wave 16x64 bf16, swizzled

  const int tid = threadIdx.x;
  const int w = tid >> 6, l = tid & 63;
  const int lh = l >> 4, ll = l & 15;
  const int ebase = blockIdx.x * 256 + w * 64;

  // phase 0: one edge per lane — claim slot + gather src embedding
  {
    int e  = ebase + l;
    int ec = min(e, E - 1);
    int srcn = ei[ec];
    int tgtn = ei[E + ec];
    int p = 0;
    if (e < E) p = atomicAdd(&cursor[tgtn], 1);
    pos_lds[w][l] = p;
    const float4* er = reinterpret_cast<const float4*>(emb) + (size_t)srcn * 4;
    float4 v0 = er[0], v1 = er[1], v2 = er[2], v3 = er[3];
    float* xr = xe_lds[w][l];
    xr[0]=v0.x;  xr[1]=v0.y;  xr[2]=v0.z;  xr[3]=v0.w;
    xr[4]=v1.x;  xr[5]=v1.y;  xr[6]=v1.z;  xr[7]=v1.w;
    xr[8]=v2.x;  xr[9]=v2.y;  xr[10]=v2.z; xr[11]=v2.w;
    xr[12]=v3.x; xr[13]=v3.y; xr[14]=v3.z; xr[15]=v3.w;
  }

  // weight fragments, VGPR-resident (L2-hot, loaded once per wave)
  s16x8 b1f[4];
#pragma unroll
  for (int ct = 0; ct < 4; ct++)
    b1f[ct] = *reinterpret_cast<const s16x8*>(W1c + (ct * 16 + ll) * 32 + lh * 8);
  s16x8 b2f[8][2];
#pragma unroll
  for (int ct = 0; ct < 8; ct++)
#pragma unroll
    for (int kt = 0; kt < 2; kt++)
      b2f[ct][kt] = *reinterpret_cast<const s16x8*>(W2c + (ct * 16 + ll) * 64 + kt * 32 + lh * 8);
  float b1v[4], b2v[8];
#pragma unroll
  for (int ct = 0; ct < 4; ct++) b1v[ct] = b1[ct * 16 + ll];
#pragma unroll
  for (int ct = 0; ct < 8; ct++) b2v[ct] = b2[ct * 16 + ll];

  // prefetch attr fragments for all 4 M-tiles (hide HBM latency once)
  float4 pa[4][2];
#pragma unroll
  for (int mt = 0; mt < 4; mt++) {
    int rowA = min(ebase + mt * 16 + ll, E - 1);
    const float4* ap = reinterpret_cast<const float4*>(attr + (size_t)rowA * EDIM + lh * 8);
    pa[mt][0] = ap[0];
    pa[mt][1] = ap[1];
  }

  const int ib = (l >> 3) & 1;
  const f32x4 z = {0.f, 0.f, 0.f, 0.f};

#pragma unroll
  for (int mt = 0; mt < 4; mt++) {
    s16x8 a1f;
    a1f[0]=f2b(pa[mt][0].x); a1f[1]=f2b(pa[mt][0].y);
    a1f[2]=f2b(pa[mt][0].z); a1f[3]=f2b(pa[mt][0].w);
    a1f[4]=f2b(pa[mt][1].x); a1f[5]=f2b(pa[mt][1].y);
    a1f[6]=f2b(pa[mt][1].z); a1f[7]=f2b(pa[mt][1].w);

    // GEMM1 + bias + relu -> H_lds (swizzled, wave-private, no barrier needed)
#pragma unroll
    for (int ct = 0; ct < 4; ct++) {
      f32x4 c1 = __builtin_amdgcn_mfma_f32_16x16x32_bf16(a1f, b1f[ct], z, 0, 0, 0);
#pragma unroll
      for (int reg = 0; reg < 4; reg++) {
        float h = fmaxf(c1[reg] + b1v[ct], 0.f);
        int rr = lh * 4 + reg;
        int byte = rr * 128 + (ct * 16 + ll) * 2;
        byte ^= (rr & 7) << 4;
        *reinterpret_cast<short*>(reinterpret_cast<char*>(H_lds[w]) + byte) = f2b(h);
      }
    }
    // A2 fragments (same-wave LDS RAW: compiler inserts lgkmcnt)
    s16x8 a2f[2];
#pragma unroll
    for (int kt = 0; kt < 2; kt++) {
      int rr = ll;
      int byte = rr * 128 + kt * 64 + lh * 16;
      byte ^= (rr & 7) << 4;
      a2f[kt] = *reinterpret_cast<const s16x8*>(reinterpret_cast<char*>(H_lds[w]) + byte);
    }
    // GEMM2 fused with epilogue dot against xe
    float mp0 = 0.f, mp1 = 0.f, mp2 = 0.f, mp3 = 0.f;
#pragma unroll
    for (int ct = 0; ct < 8; ct++) {
      f32x4 c2 = __builtin_amdgcn_mfma_f32_16x16x32_bf16(a2f[0], b2f[ct][0], z, 0, 0, 0);
      c2 = __builtin_amdgcn_mfma_f32_16x16x32_bf16(a2f[1], b2f[ct][1], c2, 0, 0, 0);
      int i  = ib + 2 * ct;
      int rb = mt * 16 + lh * 4;
      mp0 = fmaf(xe_lds[w][rb + 0][i], c2[0] + b2v[ct], mp0);
      mp1 = fmaf(xe_lds[w][rb + 1][i], c2[1] + b2v[ct], mp1);
      mp2 = fmaf(xe_lds[w][rb + 2][i], c2[2] + b2v[ct], mp2);
      mp3 = fmaf(xe_lds[w][rb + 3][i], c2[3] + b2v[ct], mp3);
    }
    mp0 += __shfl_xor(mp0, 8, 64);
    mp1 += __shfl_xor(mp1, 8, 64);
    mp2 += __shfl_xor(mp2, 8, 64);
    mp3 += __shfl_xor(mp3, 8, 64);
    if ((l & 8) == 0) {
      int o  = l & 7;
      int rb = mt * 16 + lh * 4;
      float mv[4] = {mp0, mp1, mp2, mp3};
#pragma unroll
      for (int reg = 0; reg < 4; reg++) {
        int e = ebase + rb + reg;
        if (e < E) ms[(size_t)pos_lds[w][rb + reg] * LAT + o] = mv[reg];
      }
    }
  }
}

// ---------------------------------------------------------------------------
// Aggregate contiguous messages + root weight -> latent (unchanged)
// ---------------------------------------------------------------------------
__global__ __launch_bounds__(256) void agg_latent_kernel(
    const float* __restrict__ emb, const float* __restrict__ ms,
    const int* __restrict__ offs, const int* __restrict__ deg,
    const float* __restrict__ rootW, const float* __restrict__ convb,
    float* __restrict__ latent, int N) {
  int n = blockIdx.x * blockDim.x + threadIdx.x;
  if (n >= N) return;
  int start = offs[n];
  int d = deg[n];

  float r[LAT];
#pragma unroll
  for (int o = 0; o < LAT; o++) r[o] = 0.f;

  const float4* mp = reinterpret_cast<const float4*>(ms);
  for (int j = 0; j < d; j++) {
    float4 a = mp[(size_t)(start + j) * 2];
    float4 b = mp[(size_t)(start + j) * 2 + 1];
    r[0] += a.x; r[1] += a.y; r[2] += a.z; r[3] += a.w;
    r[4] += b.x; r[5] += b.y; r[6] += b.z; r[7] += b.w;
  }

  float inv = 1.f / fmaxf((float)d, 1.f);
#pragma unroll
  for (int o = 0; o < LAT; o++) r[o] = fmaf(r[o], inv, convb[o]);

  float x[EMB];
  const float4* np4 = reinterpret_cast<const float4*>(emb) + (size_t)n * (EMB / 4);
#pragma unroll
  for (int i = 0; i < EMB / 4; i++) {
    float4 v = np4[i];
    x[4 * i + 0] = v.x; x[4 * i + 1] = v.y; x[4 * i + 2] = v.z; x[4 * i + 3] = v.w;
  }
#pragma unroll
  for (int i = 0; i < EMB; i++)
#pragma unroll
    for (int o = 0; o < LAT; o++) r[o] = fmaf(x[i], rootW[i * LAT + o], r[o]);

  float4* lp = reinterpret_cast<float4*>(latent) + (size_t)n * 2;
  lp[0] = make_float4(r[0], r[1], r[2], r[3]);
  lp[1] = make_float4(r[4], r[5], r[6], r[7]);
}

// ---------------------------------------------------------------------------
// Decoder: MFMA. GEMM1 (E,16 zero-padded to K=32)@(16,64) relu ->
// H (LDS swizzled) -> GEMM2 (E,64)@(64,32) + db2 -> out (coalesced stores).
// ---------------------------------------------------------------------------
__global__ __launch_bounds__(256, 2) void dec_mfma_kernel(
    const int* __restrict__ ei, const float* __restrict__ lat,
    const short* __restrict__ dW1c, const float* __restrict__ db1,
    const short* __restrict__ dW2c, const float* __restrict__ db2,
    float* __restrict__ out, int E) {
  __shared__ short H_lds[4][16 * 64];
  const int tid = threadIdx.x;
  const int w = tid >> 6, l = tid & 63;
  const int lh = l >> 4, ll = l & 15;
  const int ebase = blockIdx.x * 256 + w * 64;

  s16x8 b1f[4];
#pragma unroll
  for (int ct = 0; ct < 4; ct++) {
    if (lh < 2)
      b1f[ct] = *reinterpret_cast<const s16x8*>(dW1c + (ct * 16 + ll) * 16 + lh * 8);
    else
      b1f[ct] = (s16x8){0, 0, 0, 0, 0, 0, 0, 0};
  }
  s16x8 b2f[2][2];
#pragma unroll
  for (int ct = 0; ct < 2; ct++)
#pragma unroll
    for (int kt = 0; kt < 2; kt++)
      b2f[ct][kt] = *reinterpret_cast<const s16x8*>(dW2c + (ct * 16 + ll) * 64 + kt * 32 + lh * 8);
  float b1v[4], b2v[2];
#pragma unroll
  for (int ct = 0; ct < 4; ct++) b1v[ct] = db1[ct * 16 + ll];
#pragma unroll
  for (int ct = 0; ct < 2; ct++) b2v[ct] = db2[ct * 16 + ll];

  // prefetch latent rows: lh=0 -> src, lh=1 -> tgt, lh>=2 unused (zero pad)
  float4 pl[4][2];
#pragma unroll
  for (int mt = 0; mt < 4; mt++) {
    if (lh < 2) {
      int rowA = min(ebase + mt * 16 + ll, E - 1);
      int node = ei[(lh == 0 ? 0 : E) + rowA];
      const float4* lp = reinterpret_cast<const float4*>(lat + (size_t)node * LAT);
      pl[mt][0] = lp[0];
      pl[mt][1] = lp[1];
    } else {
      pl[mt][0] = make_float4(0.f, 0.f, 0.f, 0.f);
      pl[mt][1] = make_float4(0.f, 0.f, 0.f, 0.f);
    }
  }

  const f32x4 z = {0.f, 0.f, 0.f, 0.f};

#pragma unroll
  for (int mt = 0; mt < 4; mt++) {
    s16x8 af = (s16x8){0, 0, 0, 0, 0, 0, 0, 0};
    if (lh < 2) {
      af[0]=f2b(pl[mt][0].x); af[1]=f2b(pl[mt][0].y);
      af[2]=f2b(pl[mt][0].z); af[3]=f2b(pl[mt][0].w);
      af[4]=f2b(pl[mt][1].x); af[5]=f2b(pl[mt][1].y);
      af[6]=f2b(pl[mt][1].z); af[7]=f2b(pl[mt][1].w);
    }
#pragma unroll
    for (int ct = 0; ct < 4; ct++) {
      f32x4 c1 = __builtin_amdgcn_mfma_f32_16x16x32_bf16(af, b1f[ct], z, 0, 0, 0);
#pragma unroll
      for (int reg = 0; reg < 4; reg++) {
        float h = fmaxf(c1[reg] + b1v[ct], 0.f);
        int rr = lh * 4 + reg;
        int byte = rr * 128 + (ct * 16 + ll) * 2;
        byte ^= (rr & 7) << 4;
        *reinterpret_cast<short*>(reinterpret_cast<char*>(H_lds[w]) + byte) = f2b(h);
      }
    }
    s16x8 a2f[2];
#pragma unroll
    for (int kt = 0; kt < 2; kt++) {
      int rr = ll;
      int byte = rr * 128 + kt * 64 + lh * 16;
      byte ^= (rr & 7) << 4;
      a2f[kt] = *reinterpret_cast<const s16x8*>(reinterpret_cast<char*>(H_lds[w]) + byte);
    }
#pragma unroll
    for (int ct = 0; ct < 2; ct++) {
      f32x4 c2 = __builtin_amdgcn_mfma_f32_16x16x32_bf16(a2f[0], b2f[ct][0], z, 0, 0, 0);
      c2 = __builtin_amdgcn_mfma_f32_16x16x32_bf16(a2f[1], b2f[ct][1], c2, 0, 0, 0);
#pragma unroll
      for (int reg = 0; reg < 4; reg++) {
        int e = ebase + mt * 16 + lh * 4 + reg;
        if (e < E) out[(size_t)e * EDIM + ct * 16 + ll] = c2[reg] + b2v[ct];
      }
    }
  }
}

// ---------------------------------------------------------------------------
extern "C" void kernel_launch(void* const* d_in, const int* in_sizes, int n_in,
                              void* d_out, int out_size, void* d_ws, size_t ws_size,
                              hipStream_t stream) {
  const int*   ei    = (const int*)  d_in[0];
  const float* attr  = (const float*)d_in[1];
  const float* emb   = (const float*)d_in[2];
  const float* ewW1  = (const float*)d_in[3];
  const float* ewb1  = (const float*)d_in[4];
  const float* ewW2  = (const float*)d_in[5];
  const float* ewb2  = (const float*)d_in[6];
  const float* rootW = (const float*)d_in[7];
  const float* convb = (const float*)d_in[8];
  const float* dW1   = (const float*)d_in[9];
  const float* db1   = (const float*)d_in[10];
  const float* dW2   = (const float*)d_in[11];
  const float* db2   = (const float*)d_in[12];
  float* out = (float*)d_out;

  const int E  = in_sizes[0] / 2;
  const int N  = in_sizes[2] / EMB;
  const int NB = (N + SCAN_TILE - 1) / SCAN_TILE;

  // workspace layout (weights first: 16B-aligned fragment loads)
  short* W1c  = (short*)d_ws;               // 2048
  short* W2c  = W1c + 64 * 32;              // 8192
  short* dW1c = W2c + 128 * 64;             // 1024
  short* dW2c = dW1c + 64 * 16;             // 2048   (13312 shorts = 26624 B)
  float* ms   = (float*)(dW2c + 32 * 64);   // E*8
  float* lat  = ms + (size_t)E * LAT;       // N*8
  int*   deg    = (int*)(lat + (size_t)N * LAT);
  int*   loc    = deg + N;
  int*   offs   = loc + N;
  int*   cursor = offs + N;
  int*   bsum   = cursor + N;               // NB

  const int blocks_e  = (E + 255) / 256;
  const int blocks_n  = (N + 255) / 256;
  const int blocks_t  = (E + 255) / 256;    // 256 edges per MFMA block

  hipMemsetAsync(deg, 0, (size_t)N * sizeof(int), stream);
  prep_kernel<<<32, 256, 0, stream>>>(ewW1, ewW2, dW1, dW2, W1c, W2c, dW1c, dW2c);
  hist_kernel<<<blocks_e, 256, 0, stream>>>(ei, deg, E);
  scan1_kernel<<<NB, SCAN_BLK, 0, stream>>>(deg, loc, bsum, N);
  scan2_kernel<<<1, 64, 0, stream>>>(bsum, NB);
  scan3_kernel<<<blocks_n, 256, 0, stream>>>(loc, bsum, offs, cursor, N);
  enc_mfma_kernel<<<blocks_t, 256, 0, stream>>>(ei, attr, emb, W1c, ewb1, W2c, ewb2,
                                                cursor, ms, E);
  agg_latent_kernel<<<blocks_n, 256, 0, stream>>>(emb, ms, offs, deg, rootW, convb,
                                                  lat, N);
  dec_mfma_kernel<<<blocks_t, 256, 0, stream>>>(ei, lat, dW1c, db1, dW2c, db2, out, E);
}

// Round 4
// 308.952 us; speedup vs baseline: 3.3692x; 1.1772x over previous
//
#include <hip/hip_runtime.h>
#include <hip/hip_bf16.h>

typedef __attribute__((ext_vector_type(8))) short  s16x8;
typedef __attribute__((ext_vector_type(4))) float  f32x4;

constexpr int EMB  = 16;
constexpr int LAT  = 8;
constexpr int EDIM = 32;
constexpr int HID  = 64;

constexpr int SCAN_BLK   = 256;
constexpr int SCAN_ITEMS = 4;
constexpr int SCAN_TILE  = SCAN_BLK * SCAN_ITEMS;  // 1024

__device__ __forceinline__ short f2b(float f) {
  __hip_bfloat16 h = __float2bfloat16(f);
  return __builtin_bit_cast(short, h);
}

// ---------------------------------------------------------------------------
// Prep:
//  W1c  [hid][edim]  = W1^T  (identity k-map, used as A of GEMM1')
//  W2p  permuted W2 for GEMM2 B-fragments with k-map
//       g(kt,lh,j) = (kt*2+(j>>2))*16 + lh*4 + (j&3)
//       layout: [(ct2*2+kt)*4+lh][ll][j]  (8 shorts contiguous per lane)
//  dW1c [hid][16]    = dec_W1^T
//  dW2p permuted dec_W2, same g, out cols 32 (ct2 in 0..1)
// ---------------------------------------------------------------------------
__global__ void prep_kernel(const float* __restrict__ W1, const float* __restrict__ W2,
                            const float* __restrict__ dW1, const float* __restrict__ dW2,
                            short* __restrict__ W1c, short* __restrict__ W2p,
                            short* __restrict__ dW1c, short* __restrict__ dW2p) {
  int t = blockIdx.x * blockDim.x + threadIdx.x;
  if (t < 64 * 32)  { int c = t / 32, k = t % 32; W1c[t]  = f2b(W1[k * 64 + c]); }
  if (t < 8192) {
    int ct2 = t >> 10, kt = (t >> 9) & 1, lh = (t >> 7) & 3, ll = (t >> 3) & 15, j = t & 7;
    int k = (kt * 2 + (j >> 2)) * 16 + lh * 4 + (j & 3);
    W2p[t] = f2b(W2[k * 128 + ct2 * 16 + ll]);
  }
  if (t < 64 * 16)  { int c = t / 16, k = t % 16; dW1c[t] = f2b(dW1[k * 64 + c]); }
  if (t < 2048) {
    int ct2 = t >> 10, kt = (t >> 9) & 1, lh = (t >> 7) & 3, ll = (t >> 3) & 15, j = t & 7;
    int k = (kt * 2 + (j >> 2)) * 16 + lh * 4 + (j & 3);
    dW2p[t] = f2b(dW2[k * 32 + ct2 * 16 + ll]);
  }
}

// ---------------------------------------------------------------------------
// CSR build: histogram + exclusive scan
// ---------------------------------------------------------------------------
__global__ __launch_bounds__(256) void hist_kernel(const int* __restrict__ ei,
                                                   int* __restrict__ deg, int E) {
  int e = blockIdx.x * blockDim.x + threadIdx.x;
  if (e < E) atomicAdd(&deg[ei[E + e]], 1);
}

__global__ __launch_bounds__(SCAN_BLK) void scan1_kernel(
    const int* __restrict__ deg, int* __restrict__ loc,
    int* __restrict__ bsum, int N) {
  __shared__ int sh[SCAN_BLK];
  int tid  = threadIdx.x;
  int base = blockIdx.x * SCAN_TILE + tid * SCAN_ITEMS;
  int v[SCAN_ITEMS];
  int s = 0;
#pragma unroll
  for (int j = 0; j < SCAN_ITEMS; j++) {
    v[j] = (base + j < N) ? deg[base + j] : 0;
    s += v[j];
  }
  sh[tid] = s;
  __syncthreads();
  for (int off = 1; off < SCAN_BLK; off <<= 1) {
    int t = (tid >= off) ? sh[tid - off] : 0;
    __syncthreads();
    sh[tid] += t;
    __syncthreads();
  }
  int p = sh[tid] - s;
#pragma unroll
  for (int j = 0; j < SCAN_ITEMS; j++) {
    if (base + j < N) loc[base + j] = p;
    p += v[j];
  }
  if (tid == SCAN_BLK - 1) bsum[blockIdx.x] = sh[tid];
}

// parallel single-block scan over the (<=1024) block sums
__global__ __launch_bounds__(SCAN_BLK) void scan2_kernel(int* __restrict__ bsum, int NB) {
  __shared__ int sh[SCAN_BLK];
  int tid  = threadIdx.x;
  int base = tid * SCAN_ITEMS;
  int v[SCAN_ITEMS];
  int s = 0;
#pragma unroll
  for (int j = 0; j < SCAN_ITEMS; j++) {
    v[j] = (base + j < NB) ? bsum[base + j] : 0;
    s += v[j];
  }
  sh[tid] = s;
  __syncthreads();
  for (int off = 1; off < SCAN_BLK; off <<= 1) {
    int t = (tid >= off) ? sh[tid - off] : 0;
    __syncthreads();
    sh[tid] += t;
    __syncthreads();
  }
  int p = sh[tid] - s;
#pragma unroll
  for (int j = 0; j < SCAN_ITEMS; j++) {
    if (base + j < NB) bsum[base + j] = p;
    p += v[j];
  }
}

__global__ __launch_bounds__(256) void scan3_kernel(
    const int* __restrict__ loc, const int* __restrict__ bsum,
    int* __restrict__ offs, int* __restrict__ cursor, int N) {
  int i = blockIdx.x * blockDim.x + threadIdx.x;
  if (i < N) {
    int v = loc[i] + bsum[i / SCAN_TILE];
    offs[i] = v;
    cursor[i] = v;
  }
}

// ---------------------------------------------------------------------------
// Encoder. Per wave: 64 edges in 4 tiles of 16.
// GEMM1' (transposed): H^T = W1^T @ attr^T  ->  lane(ll,lh) holds
//   H[edge=ll][hid=ct*16+4lh+reg]  (a full H row per lane, no transpose!)
// GEMM2: A2 slots filled in-register via k-map g; B2 = pre-permuted W2p.
// Epilogue: msg[o] = sum_i xe[i]*(P[i*8+o]+b2[i*8+o]), shfl_xor(8) pair-reduce.
// ---------------------------------------------------------------------------
__global__ __launch_bounds__(256, 2) void enc_mfma_kernel(
    const int* __restrict__ ei, const float* __restrict__ attr,
    const float* __restrict__ emb,
    const short* __restrict__ W1c, const float* __restrict__ b1,
    const short* __restrict__ W2p, const float* __restrict__ b2,
    int* __restrict__ cursor, float* __restrict__ ms, int E) {
  __shared__ float xe_lds[4][64][17];
  __shared__ int   pos_lds[4][64];

  const int tid = threadIdx.x;
  const int w = tid >> 6, l = tid & 63;
  const int lh = l >> 4, ll = l & 15;
  const int ib = (l >> 3) & 1;
  const int ebase = blockIdx.x * 256 + w * 64;

  // phase 0: one edge per lane — claim slot + gather src embedding
  {
    int e  = ebase + l;
    int ec = min(e, E - 1);
    int srcn = ei[ec];
    int tgtn = ei[E + ec];
    int p = 0;
    if (e < E) p = atomicAdd(&cursor[tgtn], 1);
    pos_lds[w][l] = p;
    const float4* er = reinterpret_cast<const float4*>(emb) + (size_t)srcn * 4;
    float4 v0 = er[0], v1 = er[1], v2 = er[2], v3 = er[3];
    float* xr = xe_lds[w][l];
    xr[0]=v0.x;  xr[1]=v0.y;  xr[2]=v0.z;  xr[3]=v0.w;
    xr[4]=v1.x;  xr[5]=v1.y;  xr[6]=v1.z;  xr[7]=v1.w;
    xr[8]=v2.x;  xr[9]=v2.y;  xr[10]=v2.z; xr[11]=v2.w;
    xr[12]=v3.x; xr[13]=v3.y; xr[14]=v3.z; xr[15]=v3.w;
  }

  // weights, VGPR-resident
  s16x8 b1f[4];
#pragma unroll
  for (int ct = 0; ct < 4; ct++)
    b1f[ct] = *reinterpret_cast<const s16x8*>(W1c + (ct * 16 + ll) * 32 + lh * 8);
  s16x8 b2f[8][2];
#pragma unroll
  for (int ct = 0; ct < 8; ct++)
#pragma unroll
    for (int kt = 0; kt < 2; kt++)
      b2f[ct][kt] = *reinterpret_cast<const s16x8*>(W2p + ((ct * 2 + kt) * 4 + lh) * 128 + ll * 8);
  // biases: b1 per (ct,reg) -> hid = ct*16 + lh*4 + reg ; b2 per ct2 -> col = ct2*16+ll
  float4 b1v[4];
#pragma unroll
  for (int ct = 0; ct < 4; ct++)
    b1v[ct] = *reinterpret_cast<const float4*>(b1 + ct * 16 + lh * 4);
  float b2v[8];
#pragma unroll
  for (int ct = 0; ct < 8; ct++) b2v[ct] = b2[ct * 16 + ll];

  // prefetch attr fragments for all 4 tiles (B-operand of GEMM1': edge=ll)
  float4 pa[4][2];
#pragma unroll
  for (int mt = 0; mt < 4; mt++) {
    int rowA = min(ebase + mt * 16 + ll, E - 1);
    const float4* ap = reinterpret_cast<const float4*>(attr + (size_t)rowA * EDIM + lh * 8);
    pa[mt][0] = ap[0];
    pa[mt][1] = ap[1];
  }

  const f32x4 z = {0.f, 0.f, 0.f, 0.f};

#pragma unroll
  for (int mt = 0; mt < 4; mt++) {
    s16x8 af;
    af[0]=f2b(pa[mt][0].x); af[1]=f2b(pa[mt][0].y);
    af[2]=f2b(pa[mt][0].z); af[3]=f2b(pa[mt][0].w);
    af[4]=f2b(pa[mt][1].x); af[5]=f2b(pa[mt][1].y);
    af[6]=f2b(pa[mt][1].z); af[7]=f2b(pa[mt][1].w);

    // GEMM1' : c1t[ct] = (W1^T tile ct) @ attr^T  -> H^T
    f32x4 c1t[4];
#pragma unroll
    for (int ct = 0; ct < 4; ct++)
      c1t[ct] = __builtin_amdgcn_mfma_f32_16x16x32_bf16(b1f[ct], af, z, 0, 0, 0);

    // bias + relu + bf16, all in-lane
    short hb[4][4];
    {
      float bv0, bv1, bv2, bv3;
#pragma unroll
      for (int ct = 0; ct < 4; ct++) {
        bv0 = b1v[ct].x; bv1 = b1v[ct].y; bv2 = b1v[ct].z; bv3 = b1v[ct].w;
        hb[ct][0] = f2b(fmaxf(c1t[ct][0] + bv0, 0.f));
        hb[ct][1] = f2b(fmaxf(c1t[ct][1] + bv1, 0.f));
        hb[ct][2] = f2b(fmaxf(c1t[ct][2] + bv2, 0.f));
        hb[ct][3] = f2b(fmaxf(c1t[ct][3] + bv3, 0.f));
      }
    }
    // pack A2 fragments per k-map g (pure register shuffle, compile-time)
    s16x8 a2f[2];
#pragma unroll
    for (int j = 0; j < 8; j++) a2f[0][j] = hb[(j >> 2)][j & 3];
#pragma unroll
    for (int j = 0; j < 8; j++) a2f[1][j] = hb[2 + (j >> 2)][j & 3];

    // GEMM2 + fused epilogue dot against xe
    float mp0 = 0.f, mp1 = 0.f, mp2 = 0.f, mp3 = 0.f;
    const int rb = mt * 16 + lh * 4;
#pragma unroll
    for (int ct = 0; ct < 8; ct++) {
      f32x4 c2 = __builtin_amdgcn_mfma_f32_16x16x32_bf16(a2f[0], b2f[ct][0], z, 0, 0, 0);
      c2 = __builtin_amdgcn_mfma_f32_16x16x32_bf16(a2f[1], b2f[ct][1], c2, 0, 0, 0);
      int i = ib + 2 * ct;
      mp0 = fmaf(xe_lds[w][rb + 0][i], c2[0] + b2v[ct], mp0);
      mp1 = fmaf(xe_lds[w][rb + 1][i], c2[1] + b2v[ct], mp1);
      mp2 = fmaf(xe_lds[w][rb + 2][i], c2[2] + b2v[ct], mp2);
      mp3 = fmaf(xe_lds[w][rb + 3][i], c2[3] + b2v[ct], mp3);
    }
    mp0 += __shfl_xor(mp0, 8, 64);
    mp1 += __shfl_xor(mp1, 8, 64);
    mp2 += __shfl_xor(mp2, 8, 64);
    mp3 += __shfl_xor(mp3, 8, 64);
    if ((l & 8) == 0) {
      int o = l & 7;
      float mv[4] = {mp0, mp1, mp2, mp3};
#pragma unroll
      for (int reg = 0; reg < 4; reg++) {
        int e = ebase + rb + reg;
        if (e < E) ms[(size_t)pos_lds[w][rb + reg] * LAT + o] = mv[reg];
      }
    }
  }
}

// ---------------------------------------------------------------------------
// Aggregate contiguous messages + root weight -> latent
// ---------------------------------------------------------------------------
__global__ __launch_bounds__(256) void agg_latent_kernel(
    const float* __restrict__ emb, const float* __restrict__ ms,
    const int* __restrict__ offs, const int* __restrict__ deg,
    const float* __restrict__ rootW, const float* __restrict__ convb,
    float* __restrict__ latent, int N) {
  int n = blockIdx.x * blockDim.x + threadIdx.x;
  if (n >= N) return;
  int start = offs[n];
  int d = deg[n];

  float r[LAT];
#pragma unroll
  for (int o = 0; o < LAT; o++) r[o] = 0.f;

  const float4* mp = reinterpret_cast<const float4*>(ms);
  for (int j = 0; j < d; j++) {
    float4 a = mp[(size_t)(start + j) * 2];
    float4 b = mp[(size_t)(start + j) * 2 + 1];
    r[0] += a.x; r[1] += a.y; r[2] += a.z; r[3] += a.w;
    r[4] += b.x; r[5] += b.y; r[6] += b.z; r[7] += b.w;
  }

  float inv = 1.f / fmaxf((float)d, 1.f);
#pragma unroll
  for (int o = 0; o < LAT; o++) r[o] = fmaf(r[o], inv, convb[o]);

  float x[EMB];
  const float4* np4 = reinterpret_cast<const float4*>(emb) + (size_t)n * (EMB / 4);
#pragma unroll
  for (int i = 0; i < EMB / 4; i++) {
    float4 v = np4[i];
    x[4 * i + 0] = v.x; x[4 * i + 1] = v.y; x[4 * i + 2] = v.z; x[4 * i + 3] = v.w;
  }
#pragma unroll
  for (int i = 0; i < EMB; i++)
#pragma unroll
    for (int o = 0; o < LAT; o++) r[o] = fmaf(x[i], rootW[i * LAT + o], r[o]);

  float4* lp = reinterpret_cast<float4*>(latent) + (size_t)n * 2;
  lp[0] = make_float4(r[0], r[1], r[2], r[3]);
  lp[1] = make_float4(r[4], r[5], r[6], r[7]);
}

// ---------------------------------------------------------------------------
// Decoder: same transposed-GEMM1 trick; zero LDS, pure register MFMA chain.
// ---------------------------------------------------------------------------
__global__ __launch_bounds__(256, 4) void dec_mfma_kernel(
    const int* __restrict__ ei, const float* __restrict__ lat,
    const short* __restrict__ dW1c, const float* __restrict__ db1,
    const short* __restrict__ dW2p, const float* __restrict__ db2,
    float* __restrict__ out, int E) {
  const int tid = threadIdx.x;
  const int w = tid >> 6, l = tid & 63;
  const int lh = l >> 4, ll = l & 15;
  const int ebase = blockIdx.x * 256 + w * 64;

  s16x8 b1f[4];
#pragma unroll
  for (int ct = 0; ct < 4; ct++) {
    if (lh < 2)
      b1f[ct] = *reinterpret_cast<const s16x8*>(dW1c + (ct * 16 + ll) * 16 + lh * 8);
    else
      b1f[ct] = (s16x8){0, 0, 0, 0, 0, 0, 0, 0};
  }
  s16x8 b2f[2][2];
#pragma unroll
  for (int ct = 0; ct < 2; ct++)
#pragma unroll
    for (int kt = 0; kt < 2; kt++)
      b2f[ct][kt] = *reinterpret_cast<const s16x8*>(dW2p + ((ct * 2 + kt) * 4 + lh) * 128 + ll * 8);
  float4 b1v[4];
#pragma unroll
  for (int ct = 0; ct < 4; ct++)
    b1v[ct] = *reinterpret_cast<const float4*>(db1 + ct * 16 + lh * 4);
  float b2v[2];
#pragma unroll
  for (int ct = 0; ct < 2; ct++) b2v[ct] = db2[ct * 16 + ll];

  // prefetch latent halves: lh=0 -> src, lh=1 -> tgt, lh>=2 zero pad (k 16..31)
  float4 pl[4][2];
#pragma unroll
  for (int mt = 0; mt < 4; mt++) {
    if (lh < 2) {
      int rowA = min(ebase + mt * 16 + ll, E - 1);
      int node = ei[(lh == 0 ? 0 : E) + rowA];
      const float4* lp = reinterpret_cast<const float4*>(lat + (size_t)node * LAT);
      pl[mt][0] = lp[0];
      pl[mt][1] = lp[1];
    } else {
      pl[mt][0] = make_float4(0.f, 0.f, 0.f, 0.f);
      pl[mt][1] = make_float4(0.f, 0.f, 0.f, 0.f);
    }
  }

  const f32x4 z = {0.f, 0.f, 0.f, 0.f};

#pragma unroll
  for (int mt = 0; mt < 4; mt++) {
    s16x8 af = (s16x8){0, 0, 0, 0, 0, 0, 0, 0};
    if (lh < 2) {
      af[0]=f2b(pl[mt][0].x); af[1]=f2b(pl[mt][0].y);
      af[2]=f2b(pl[mt][0].z); af[3]=f2b(pl[mt][0].w);
      af[4]=f2b(pl[mt][1].x); af[5]=f2b(pl[mt][1].y);
      af[6]=f2b(pl[mt][1].z); af[7]=f2b(pl[mt][1].w);
    }
    f32x4 c1t[4];
#pragma unroll
    for (int ct = 0; ct < 4; ct++)
      c1t[ct] = __builtin_amdgcn_mfma_f32_16x16x32_bf16(b1f[ct], af, z, 0, 0, 0);

    short hb[4][4];
#pragma unroll
    for (int ct = 0; ct < 4; ct++) {
      hb[ct][0] = f2b(fmaxf(c1t[ct][0] + b1v[ct].x, 0.f));
      hb[ct][1] = f2b(fmaxf(c1t[ct][1] + b1v[ct].y, 0.f));
      hb[ct][2] = f2b(fmaxf(c1t[ct][2] + b1v[ct].z, 0.f));
      hb[ct][3] = f2b(fmaxf(c1t[ct][3] + b1v[ct].w, 0.f));
    }
    s16x8 a2f[2];
#pragma unroll
    for (int j = 0; j < 8; j++) a2f[0][j] = hb[(j >> 2)][j & 3];
#pragma unroll
    for (int j = 0; j < 8; j++) a2f[1][j] = hb[2 + (j >> 2)][j & 3];

#pragma unroll
    for (int ct = 0; ct < 2; ct++) {
      f32x4 c2 = __builtin_amdgcn_mfma_f32_16x16x32_bf16(a2f[0], b2f[ct][0], z, 0, 0, 0);
      c2 = __builtin_amdgcn_mfma_f32_16x16x32_bf16(a2f[1], b2f[ct][1], c2, 0, 0, 0);
#pragma unroll
      for (int reg = 0; reg < 4; reg++) {
        int e = ebase + mt * 16 + lh * 4 + reg;
        if (e < E) out[(size_t)e * EDIM + ct * 16 + ll] = c2[reg] + b2v[ct];
      }
    }
  }
}

// ---------------------------------------------------------------------------
extern "C" void kernel_launch(void* const* d_in, const int* in_sizes, int n_in,
                              void* d_out, int out_size, void* d_ws, size_t ws_size,
                              hipStream_t stream) {
  const int*   ei    = (const int*)  d_in[0];
  const float* attr  = (const float*)d_in[1];
  const float* emb   = (const float*)d_in[2];
  const float* ewW1  = (const float*)d_in[3];
  const float* ewb1  = (const float*)d_in[4];
  const float* ewW2  = (const float*)d_in[5];
  const float* ewb2  = (const float*)d_in[6];
  const float* rootW = (const float*)d_in[7];
  const float* convb = (const float*)d_in[8];
  const float* dW1   = (const float*)d_in[9];
  const float* db1   = (const float*)d_in[10];
  const float* dW2   = (const float*)d_in[11];
  const float* db2   = (const float*)d_in[12];
  float* out = (float*)d_out;

  const int E  = in_sizes[0] / 2;
  const int N  = in_sizes[2] / EMB;
  const int NB = (N + SCAN_TILE - 1) / SCAN_TILE;

  // workspace layout (weights first: 16B-aligned fragment loads)
  short* W1c  = (short*)d_ws;               // 2048
  short* W2p  = W1c + 64 * 32;              // 8192
  short* dW1c = W2p + 8192;                 // 1024
  short* dW2p = dW1c + 64 * 16;             // 2048   (13312 shorts = 26624 B)
  float* ms   = (float*)(dW2p + 2048);      // E*8
  float* lat  = ms + (size_t)E * LAT;       // N*8
  int*   deg    = (int*)(lat + (size_t)N * LAT);
  int*   loc    = deg + N;
  int*   offs   = loc + N;
  int*   cursor = offs + N;
  int*   bsum   = cursor + N;               // NB

  const int blocks_e = (E + 255) / 256;
  const int blocks_n = (N + 255) / 256;

  hipMemsetAsync(deg, 0, (size_t)N * sizeof(int), stream);
  prep_kernel<<<32, 256, 0, stream>>>(ewW1, ewW2, dW1, dW2, W1c, W2p, dW1c, dW2p);
  hist_kernel<<<blocks_e, 256, 0, stream>>>(ei, deg, E);
  scan1_kernel<<<NB, SCAN_BLK, 0, stream>>>(deg, loc, bsum, N);
  scan2_kernel<<<1, SCAN_BLK, 0, stream>>>(bsum, NB);
  scan3_kernel<<<blocks_n, 256, 0, stream>>>(loc, bsum, offs, cursor, N);
  enc_mfma_kernel<<<blocks_e, 256, 0, stream>>>(ei, attr, emb, W1c, ewb1, W2p, ewb2,
                                                cursor, ms, E);
  agg_latent_kernel<<<blocks_n, 256, 0, stream>>>(emb, ms, offs, deg, rootW, convb,
                                                  lat, N);
  dec_mfma_kernel<<<blocks_e, 256, 0, stream>>>(ei, lat, dW1c, db1, dW2p, db2, out, E);
}